// Round 15
// baseline (732.668 us; speedup 1.0000x reference)
//
#include <hip/hip_runtime.h>
#include <hip/hip_bf16.h>
#include <math.h>

#define HIDDEN   2560
#define NUM_HEADS 80
#define HEAD_DIM 64
#define STATE    128
#define CONV_K   4
#define CHUNK    256
#define INTER    (2*HIDDEN)                 // 5120
#define CONV_DIM (INTER + 2*STATE)          // 5376
#define PROJ     (INTER + CONV_DIM + NUM_HEADS) // 10576
#define PROJ_PAD 10240                      // gate + X only
#define NBC      336
#define NBCP     384
#define EPS      1e-5f

#define BATCH 2
#define SEQ   2048
#define TOK   (BATCH*SEQ)                   // 4096
#define NC    (SEQ/CHUNK)                   // 8
#define KSPL2 8
#define KCH2  (HIDDEN/KSPL2)                // 320

#define RED_BLOCKS 1536
#define CXT_BLOCKS 5120
#define CBC_BLOCKS 4096
#define CUM_BLOCKS 1280
#define W2_BLOCKS  12800
#define ST_BLOCKS  1280
#define GK_BLOCKS  576

typedef __attribute__((ext_vector_type(8))) short bf16x8;
typedef __attribute__((ext_vector_type(4))) float f32x4;
typedef unsigned short us;

#define MFMA16(a,b,c) __builtin_amdgcn_mfma_f32_16x16x32_bf16((a),(b),(c),0,0,0)

__device__ __forceinline__ us f2bf(float f){
    union{float f;unsigned u;}v; v.f=f;
    unsigned r = v.u + 0x7fffu + ((v.u>>16)&1u);
    return (us)(r>>16);
}
__device__ __forceinline__ float bf2f(us s){
    union{unsigned u;float f;}v; v.u = ((unsigned)s)<<16; return v.f;
}
__device__ __forceinline__ void unpack8(uint4 u, float* e){
    e[0]=bf2f((us)(u.x&0xffff)); e[1]=bf2f((us)(u.x>>16));
    e[2]=bf2f((us)(u.y&0xffff)); e[3]=bf2f((us)(u.y>>16));
    e[4]=bf2f((us)(u.z&0xffff)); e[5]=bf2f((us)(u.z>>16));
    e[6]=bf2f((us)(u.w&0xffff)); e[7]=bf2f((us)(u.w>>16));
}
__device__ __forceinline__ void gld16(const void* g, void* l){
    __builtin_amdgcn_global_load_lds((const __attribute__((address_space(1))) void*)g,
                                     (__attribute__((address_space(3))) void*)l, 16, 0, 0);
}

// =============== 256x256 8-phase deep-pipelined bf16 MFMA GEMM1 =====================
// K-tile=64 split into 2 K-halves of 32; half-tile = [256][32] panel of one matrix.
// 8 phases / 2 K-tiles, 1 half-tile staged per phase (2 gld16/thread), 16 MFMA/phase,
// counted vmcnt(8) at sub1/sub3 ends, raw s_barrier, setprio. 512 thr = 8 waves 2Mx4N.
__global__ __launch_bounds__(512) void gemm1_8ph(const us* __restrict__ A,
                                                 const us* __restrict__ B,
                                                 us* __restrict__ C, int ldc) {
    __shared__ us LA[2][2][256][32];     // [tile parity][K-half][row][col]
    __shared__ us LB[2][2][256][32];
    int tid = threadIdx.x, lane = tid & 63, wid = tid >> 6;
    int wm = wid >> 2, wn = wid & 3;

    int bid   = blockIdx.y * gridDim.x + blockIdx.x;
    int xcd   = bid & 7;
    int local = bid >> 3;
    int mrows = gridDim.y >> 3;
    int bm = (xcd * mrows + (local % mrows)) * 256;
    int bn = (local / mrows) * 256;

    f32x4 acc[8][4];
    #pragma unroll
    for (int i=0;i<8;i++)
        #pragma unroll
        for (int j=0;j<4;j++) acc[i][j] = (f32x4){0.f,0.f,0.f,0.f};

    const int NT = HIDDEN/64;            // 40

    #define STGA(TT,KH) { _Pragma("unroll")                                        \
        for (int q=0;q<2;q++){                                                     \
            int brow=(wid*2+q)*16; int row=brow+(lane>>2);                         \
            int sl=(lane&3)^((row>>1)&3);                                          \
            gld16(A + (size_t)(bm+row)*HIDDEN + (TT)*64 + (KH)*32 + sl*8,          \
                  &LA[(TT)&1][KH][brow][0]); } }
    #define STGB(TT,KH) { _Pragma("unroll")                                        \
        for (int q=0;q<2;q++){                                                     \
            int brow=(wid*2+q)*16; int row=brow+(lane>>2);                         \
            int sl=(lane&3)^((row>>1)&3);                                          \
            gld16(B + (size_t)(bn+row)*HIDDEN + (TT)*64 + (KH)*32 + sl*8,          \
                  &LB[(TT)&1][KH][brow][0]); } }

    // prologue: units for phases -6..-1 of the steady-state schedule
    STGA(0,0); STGB(0,0); STGA(0,1); STGB(0,1); STGA(1,0); STGB(1,0);
    asm volatile("s_waitcnt vmcnt(8)" ::: "memory");   // Kh0(0) landed
    asm volatile("s_barrier" ::: "memory");

    for (int t = 0; t < NT; ++t) {
        int par = t & 1;
        #pragma unroll
        for (int sub = 0; sub < 4; ++sub) {
            const int kh = sub >> 1, mg = sub & 1;
            // --- frag loads (data guaranteed by prior vmcnt+barrier) ---
            bf16x8 afr[4], bfr[4];
            #pragma unroll
            for (int mi=0;mi<4;mi++){
                int row = wm*128 + (mg*4+mi)*16 + (lane&15);
                int sl  = (lane>>4) ^ ((row>>1)&3);
                afr[mi] = *(const bf16x8*)&LA[par][kh][row][sl*8];
            }
            #pragma unroll
            for (int nj=0;nj<4;nj++){
                int row = wn*64 + nj*16 + (lane&15);
                int sl  = (lane>>4) ^ ((row>>1)&3);
                bfr[nj] = *(const bf16x8*)&LB[par][kh][row][sl*8];
            }
            // --- stage 1 half-tile (target region dead since last phase) ---
            if      (sub==0) { if (t+1<NT) STGA(t+1,1); }
            else if (sub==1) { if (t+1<NT) STGB(t+1,1); }
            else if (sub==2) { if (t+2<NT) STGA(t+2,0); }
            else             { if (t+2<NT) STGB(t+2,0); }
            asm volatile("s_barrier" ::: "memory");
            __builtin_amdgcn_s_setprio(1);
            #pragma unroll
            for (int mi=0;mi<4;mi++)
                #pragma unroll
                for (int nj=0;nj<4;nj++)
                    acc[mg*4+mi][nj] = MFMA16(afr[mi], bfr[nj], acc[mg*4+mi][nj]);
            __builtin_amdgcn_s_setprio(0);
            if (sub==1 || sub==3) {
                if (t < NT-2) asm volatile("s_waitcnt vmcnt(8)" ::: "memory");
                else          asm volatile("s_waitcnt vmcnt(0)" ::: "memory");
            }
            asm volatile("s_barrier" ::: "memory");
        }
    }
    #undef STGA
    #undef STGB

    #pragma unroll
    for (int i=0;i<8;i++){
        int row0 = bm + wm*128 + i*16 + (lane>>4)*4;
        #pragma unroll
        for (int j=0;j<4;j++){
            int col = bn + wn*64 + j*16 + (lane&15);
            #pragma unroll
            for (int r=0;r<4;r++)
                C[(size_t)(row0+r)*ldc + col] = f2bf(acc[i][j][r]);
        }
    }
}

// =============== 128x128 bf16 MFMA GEMM (NT) — GEMM2 ================================
template<bool BF16OUT>
__global__ __launch_bounds__(256) void gemm_bf16(const us* __restrict__ A, int lda,
                                                 const us* __restrict__ B, int ldb,
                                                 void* __restrict__ Cv, int ldc, int K) {
    __shared__ us As[128][64];
    __shared__ us Bs[128][64];
    int tid = threadIdx.x;
    int lane = tid & 63, wid = tid >> 6;
    int wr = wid >> 1, wc = wid & 1;

    int bm, bn;
    if ((gridDim.y & 7) == 0) {
        int bid   = blockIdx.y * gridDim.x + blockIdx.x;
        int xcd   = bid & 7;
        int local = bid >> 3;
        int mrows = gridDim.y >> 3;
        bm = (xcd * mrows + (local % mrows)) * 128;
        bn = (local / mrows) * 128;
    } else {
        bm = blockIdx.y * 128;
        bn = blockIdx.x * 128;
    }

    f32x4 acc[4][4];
    #pragma unroll
    for (int i=0;i<4;i++)
        #pragma unroll
        for (int j=0;j<4;j++) acc[i][j] = (f32x4){0.f,0.f,0.f,0.f};

    int srow_off = lane >> 3;
    int sslot    = lane & 7;

    for (int k0 = 0; k0 < K; k0 += 64) {
        #pragma unroll
        for (int q=0;q<4;q++){
            int brow = (wid*4+q)*8;
            int row  = brow + srow_off;
            int sl   = sslot ^ (row & 7);
            gld16(A + (size_t)(bm + row)*lda + k0 + sl*8, &As[brow][0]);
            gld16(B + (size_t)(bn + row)*ldb + k0 + sl*8, &Bs[brow][0]);
        }
        __syncthreads();
        #pragma unroll
        for (int kk=0; kk<64; kk+=32){
            bf16x8 a[4], b[4];
            #pragma unroll
            for (int i=0;i<4;i++){
                int row = wr*64 + i*16 + (lane&15);
                int slot = ((kk>>3) + (lane>>4)) ^ (row & 7);
                a[i] = *(const bf16x8*)&As[row][slot*8];
            }
            #pragma unroll
            for (int j=0;j<4;j++){
                int row = wc*64 + j*16 + (lane&15);
                int slot = ((kk>>3) + (lane>>4)) ^ (row & 7);
                b[j] = *(const bf16x8*)&Bs[row][slot*8];
            }
            #pragma unroll
            for (int i=0;i<4;i++)
                #pragma unroll
                for (int j=0;j<4;j++)
                    acc[i][j] = MFMA16(a[i], b[j], acc[i][j]);
        }
        __syncthreads();
    }
    #pragma unroll
    for (int i=0;i<4;i++){
        int row0 = bm + wr*64 + i*16 + (lane>>4)*4;
        #pragma unroll
        for (int j=0;j<4;j++){
            int col = bn + wc*64 + j*16 + (lane&15);
            #pragma unroll
            for (int r=0;r<4;r++){
                if (BF16OUT)
                    ((us*)Cv)[(size_t)(row0+r)*ldc + col] = f2bf(acc[i][j][r]);
                else
                    ((float*)Cv)[(size_t)(row0+r)*ldc + col] = acc[i][j][r];
            }
        }
    }
}

// =============== bf16 hi/lo split-K MFMA for B/C/dt (fp32-quality) ====================
__global__ __launch_bounds__(256) void bc_splitk_mfma(const us* __restrict__ xhi,
                                                      const us* __restrict__ xlo,
                                                      const us* __restrict__ whi,
                                                      const us* __restrict__ wlo,
                                                      float* __restrict__ Cpart) {
    __shared__ us As[128][64];
    __shared__ us Bs[128][64];
    int tid = threadIdx.x;
    int lane = tid & 63, wid = tid >> 6;
    int wr = wid >> 1, wc = wid & 1;
    int bn = blockIdx.x * 128, bm = blockIdx.y * 128, z = blockIdx.z;

    f32x4 acc[4][4];
    #pragma unroll
    for (int i=0;i<4;i++)
        #pragma unroll
        for (int j=0;j<4;j++) acc[i][j] = (f32x4){0.f,0.f,0.f,0.f};

    int srow_off = lane >> 3;
    int sslot    = lane & 7;

    for (int term = 0; term < 3; ++term){
        const us* A = (term==2) ? xlo : xhi;
        const us* B = (term==0) ? wlo : whi;
        for (int k0 = z*KCH2; k0 < z*KCH2 + KCH2; k0 += 64) {
            #pragma unroll
            for (int q=0;q<4;q++){
                int brow = (wid*4+q)*8;
                int row  = brow + srow_off;
                int sl   = sslot ^ (row & 7);
                gld16(A + (size_t)(bm + row)*HIDDEN + k0 + sl*8, &As[brow][0]);
                gld16(B + (size_t)(bn + row)*HIDDEN + k0 + sl*8, &Bs[brow][0]);
            }
            __syncthreads();
            #pragma unroll
            for (int kk=0; kk<64; kk+=32){
                bf16x8 a[4], b[4];
                #pragma unroll
                for (int i=0;i<4;i++){
                    int row = wr*64 + i*16 + (lane&15);
                    int slot = ((kk>>3) + (lane>>4)) ^ (row & 7);
                    a[i] = *(const bf16x8*)&As[row][slot*8];
                }
                #pragma unroll
                for (int j=0;j<4;j++){
                    int row = wc*64 + j*16 + (lane&15);
                    int slot = ((kk>>3) + (lane>>4)) ^ (row & 7);
                    b[j] = *(const bf16x8*)&Bs[row][slot*8];
                }
                #pragma unroll
                for (int i=0;i<4;i++)
                    #pragma unroll
                    for (int j=0;j<4;j++)
                        acc[i][j] = MFMA16(a[i], b[j], acc[i][j]);
            }
            __syncthreads();
        }
    }
    float* Cz = Cpart + (size_t)z*TOK*NBCP;
    #pragma unroll
    for (int i=0;i<4;i++){
        int row0 = bm + wr*64 + i*16 + (lane>>4)*4;
        #pragma unroll
        for (int j=0;j<4;j++){
            int col = bn + wc*64 + j*16 + (lane&15);
            #pragma unroll
            for (int r=0;r<4;r++)
                Cz[(size_t)(row0+r)*NBCP + col] = acc[i][j][r];
        }
    }
}

// ---------------- fused prep: x->(xhi,xlo), w1->bf16, wbc->(hi,lo) ------------------
#define N4A ((size_t)TOK*HIDDEN/4)
#define N4B ((size_t)PROJ_PAD*HIDDEN/4)
#define N4C ((size_t)NBCP*HIDDEN/4)
__global__ __launch_bounds__(256) void prep_kernel(const float* __restrict__ x,
                                                   const float* __restrict__ in_w,
                                                   us* __restrict__ xhi,
                                                   us* __restrict__ xlo,
                                                   us* __restrict__ w1b,
                                                   us* __restrict__ wbc_hi,
                                                   us* __restrict__ wbc_lo) {
    size_t gid = (size_t)blockIdx.x*256 + threadIdx.x;
    if (gid < N4A) {
        size_t i = gid*4;
        float4 v = *(const float4*)(x + i);
        float e[4] = {v.x, v.y, v.z, v.w};
        ushort4 h, l;
        us* hp = (us*)&h;
        us* lp = (us*)&l;
        #pragma unroll
        for (int u=0;u<4;u++){
            us hv = f2bf(e[u]);
            hp[u] = hv;
            lp[u] = f2bf(e[u] - bf2f(hv));
        }
        *(ushort4*)(xhi + i) = h;
        *(ushort4*)(xlo + i) = l;
    } else if (gid < N4A + N4B) {
        size_t i = (gid - N4A)*4;
        float4 v = *(const float4*)(in_w + i);
        ushort4 o;
        o.x=f2bf(v.x); o.y=f2bf(v.y); o.z=f2bf(v.z); o.w=f2bf(v.w);
        *(ushort4*)(w1b + i) = o;
    } else {
        size_t j = gid - N4A - N4B;
        size_t i = j*4;
        int row = (int)(i / HIDDEN);
        int kk  = (int)(i % HIDDEN);
        ushort4 h, l;
        h.x=h.y=h.z=h.w=0; l.x=l.y=l.z=l.w=0;
        if (row < NBC){
            float4 v = *(const float4*)(in_w + (size_t)(2*INTER + row)*HIDDEN + kk);
            float e[4] = {v.x, v.y, v.z, v.w};
            us* hp = (us*)&h;
            us* lp = (us*)&l;
            #pragma unroll
            for (int u=0;u<4;u++){
                us hv = f2bf(e[u]);
                hp[u] = hv;
                lp[u] = f2bf(e[u] - bf2f(hv));
            }
        }
        *(ushort4*)(wbc_hi + i) = h;
        *(ushort4*)(wbc_lo + i) = l;
    }
}

// =============== MERGED: reduce_bc2 + conv_xt =======================================
__global__ __launch_bounds__(256) void mega_red_convxt(const float* __restrict__ part,
                                                       const float* __restrict__ dt_bias,
                                                       const us* __restrict__ projb,
                                                       const float* __restrict__ cw,
                                                       const float* __restrict__ cb,
                                                       float* __restrict__ outBC,
                                                       float* __restrict__ dtbuf,
                                                       us* __restrict__ XT) {
    __shared__ us raw[68][66];
    int bid = blockIdx.x;
    int tid = threadIdx.x;
    if (bid < RED_BLOCKS) {
        size_t i4 = (size_t)bid*256 + tid;
        size_t i = i4*4;
        float4 s = *(const float4*)(part + i);
        #pragma unroll
        for (int z=1; z<KSPL2; z++){
            float4 v = *(const float4*)(part + (size_t)z*TOK*NBCP + i);
            s.x += v.x; s.y += v.y; s.z += v.z; s.w += v.w;
        }
        int col = (int)(i % NBCP);
        int t   = (int)(i / NBCP);
        if (col < 256) {
            *(float4*)(outBC + (size_t)t*NBC + col) = s;
        } else if (col < NBC) {
            int h = col - 256;
            float e[4] = {s.x, s.y, s.z, s.w};
            #pragma unroll
            for (int u=0;u<4;u++){
                float xv = e[u] + dt_bias[h+u];
                float sp = (xv > 20.f) ? xv : log1pf(expf(xv));
                e[u] = fminf(fmaxf(sp, 0.f), 100.f);
            }
            float4 o; o.x=e[0]; o.y=e[1]; o.z=e[2]; o.w=e[3];
            *(float4*)(dtbuf + (size_t)t*NUM_HEADS + h) = o;
        }
    } else {
        int b3 = bid - RED_BLOCKS;
        int bx = b3 & 63, by = b3 >> 6;
        int t0 = bx * 64, d0 = by * 64;
        int b  = t0 / SEQ;
        int s0 = t0 % SEQ;
        for (int f = tid; f < 67*8; f += 256){
            int r = f >> 3, g = f & 7;
            int sp = s0 - 3 + r;
            uint4 v;
            if (sp >= 0) v = *(const uint4*)(projb + ((size_t)(b*SEQ+sp))*PROJ_PAD + INTER + d0 + g*8);
            else { v.x=0u; v.y=0u; v.z=0u; v.w=0u; }
            unsigned int* dst = (unsigned int*)&raw[r][g*8];
            dst[0]=v.x; dst[1]=v.y; dst[2]=v.z; dst[3]=v.w;
        }
        __syncthreads();
        int t = tid & 63, dg = tid >> 6;
        #pragma unroll
        for (int dd = 0; dd < 16; dd++){
            int d = dg*16 + dd;
            float acc = cb[d0+d];
            #pragma unroll
            for (int j=0;j<CONV_K;j++)
                acc += cw[(d0+d)*CONV_K+j] * bf2f(raw[t+j][d]);
            float val = acc/(1.f+expf(-acc));
            XT[((size_t)(b*INTER + d0 + d))*SEQ + s0 + t] = f2bf(val);
        }
    }
}

// =============== MERGED: conv_bc + cumsum + w2 cvt ==================================
__global__ __launch_bounds__(256) void mega_convbc_cum_w2(const float* __restrict__ projBC,
                                                          const float* __restrict__ cw,
                                                          const float* __restrict__ cb,
                                                          const float* __restrict__ dtbuf,
                                                          const float* __restrict__ A_log,
                                                          const float* __restrict__ out_w,
                                                          float* __restrict__ xBC_BC,
                                                          us* __restrict__ BT,
                                                          us* __restrict__ Cb,
                                                          float* __restrict__ A_cum,
                                                          us* __restrict__ w2b) {
    __shared__ float buf[CHUNK];
    int bid = blockIdx.x;
    int tid = threadIdx.x;
    if (bid < CBC_BLOCKS) {
        int idx = bid*256 + tid;
        int d = idx & 255;
        int t = idx >> 8;
        int b = t / SEQ, sl = t % SEQ;
        int dc = INTER + d;
        float acc = cb[dc];
        #pragma unroll
        for (int j=0;j<CONV_K;j++){
            int sp = sl - (CONV_K-1) + j;
            if (sp >= 0)
                acc += cw[dc*CONV_K+j] * projBC[((size_t)(b*SEQ+sp))*NBC + d];
        }
        float val = acc / (1.f + expf(-acc));
        xBC_BC[(size_t)t*256 + d] = val;
        if (d < 128)
            BT[((size_t)(b*128 + d))*SEQ + sl] = f2bf(val);
        else
            Cb[(size_t)t*128 + (d-128)] = f2bf(val);
    } else if (bid < CBC_BLOCKS + CUM_BLOCKS) {
        int b4 = bid - CBC_BLOCKS;
        int c = b4 & 7, h = (b4 >> 3) % 80, b = b4 / 640;
        int l = tid;
        float A = -expf(A_log[h]);
        float v = A * dtbuf[(size_t)(b*SEQ + c*CHUNK + l)*NUM_HEADS + h];
        buf[l] = v;
        __syncthreads();
        for (int off=1; off<CHUNK; off<<=1){
            float t2 = (l>=off) ? buf[l-off] : 0.f;
            __syncthreads();
            buf[l] += t2;
            __syncthreads();
        }
        A_cum[((size_t)b*NUM_HEADS + h)*SEQ + c*CHUNK + l] = buf[l];
    } else {
        size_t i4 = (size_t)(bid - CBC_BLOCKS - CUM_BLOCKS)*256 + tid;
        size_t i = i4*4;
        float4 v = *(const float4*)(out_w + i);
        ushort4 o; o.x=f2bf(v.x); o.y=f2bf(v.y); o.z=f2bf(v.z); o.w=f2bf(v.w);
        *(ushort4*)(w2b + i) = o;
    }
}

// =============== MERGED: states_mfma + g_kernel =====================================
__global__ __launch_bounds__(256) void mega_states_g(const us* __restrict__ XT,
                                                     const us* __restrict__ BT,
                                                     const float* __restrict__ dtbuf,
                                                     const float* __restrict__ A_cum,
                                                     const float* __restrict__ xBC_BC,
                                                     us* __restrict__ statesT,
                                                     us* __restrict__ G) {
    __shared__ __align__(16) char SH[33792];
    int bid = blockIdx.x;
    int tid = threadIdx.x;
    if (bid < ST_BLOCKS) {
        int c = bid & 7, h = (bid >> 3) % 80, b = bid / 640;
        us (*Asx)[64] = (us(*)[64])SH;
        us (*Bs)[64]  = (us(*)[64])(SH + 8192);
        float* wl     = (float*)(SH + 24576);
        int lane = tid & 63, wid = tid >> 6;
        {
            const float* ac = A_cum + ((size_t)(b*NUM_HEADS+h))*SEQ + c*CHUNK;
            float Alast = ac[CHUNK-1];
            wl[tid] = expf(Alast - ac[tid]) * dtbuf[((size_t)(b*SEQ + c*CHUNK + tid))*NUM_HEADS + h];
        }
        __syncthreads();
        f32x4 acc[4][2];
        #pragma unroll
        for (int i=0;i<4;i++)
            #pragma unroll
            for (int j=0;j<2;j++) acc[i][j] = (f32x4){0.f,0.f,0.f,0.f};

        for (int kc = 0; kc < 4; kc++){
            int lbase = kc*64;
            #pragma unroll
            for (int q=0;q<4;q++){
                int brow = (wid*4+q)*8;
                int row  = brow + (lane>>3);
                int sl   = (lane&7) ^ (row & 7);
                gld16(BT + ((size_t)(b*128 + row))*SEQ + c*CHUNK + lbase + sl*8, &Bs[brow][0]);
            }
            #pragma unroll
            for (int it=0; it<2; it++){
                int f = tid + it*256;
                int r = f >> 3, g = f & 7;
                uint4 v = *(const uint4*)(XT + ((size_t)(b*INTER + h*HEAD_DIM + r))*SEQ + c*CHUNK + lbase + g*8);
                float e[8]; unpack8(v, e);
                us o[8];
                #pragma unroll
                for (int u=0;u<8;u++) o[u] = f2bf(e[u] * wl[lbase + g*8 + u]);
                int slot = g ^ (r & 7);
                *(ushort4*)&Asx[r][slot*8]   = *(ushort4*)&o[0];
                *(ushort4*)&Asx[r][slot*8+4] = *(ushort4*)&o[4];
            }
            __syncthreads();
            #pragma unroll
            for (int kk=0; kk<64; kk+=32){
                bf16x8 a[4], bb[2];
                #pragma unroll
                for (int i=0;i<4;i++){
                    int row = i*16 + (lane&15);
                    int slot = ((kk>>3)+(lane>>4)) ^ (row&7);
                    a[i] = *(const bf16x8*)&Asx[row][slot*8];
                }
                #pragma unroll
                for (int j=0;j<2;j++){
                    int row = wid*32 + j*16 + (lane&15);
                    int slot = ((kk>>3)+(lane>>4)) ^ (row&7);
                    bb[j] = *(const bf16x8*)&Bs[row][slot*8];
                }
                #pragma unroll
                for (int i=0;i<4;i++)
                    #pragma unroll
                    for (int j=0;j<2;j++)
                        acc[i][j] = MFMA16(a[i], bb[j], acc[i][j]);
            }
            __syncthreads();
        }
        size_t sb = ((size_t)((b*NC + c)*NUM_HEADS + h))*(HEAD_DIM*STATE);
        #pragma unroll
        for (int i=0;i<4;i++){
            #pragma unroll
            for (int j=0;j<2;j++){
                int n = wid*32 + j*16 + (lane&15);
                int p0 = i*16 + (lane>>4)*4;
                #pragma unroll
                for (int r=0;r<4;r++)
                    statesT[sb + (size_t)(p0+r)*128 + n] = f2bf(acc[i][j][r]);
            }
        }
    } else {
        int b5 = bid - ST_BLOCKS;
        int c = b5 & 7, p = (b5 >> 3) % 36, b = b5 / 288;
        int lt = 0, a0 = 0;
        while (a0 + lt + 1 <= p) { a0 += lt + 1; lt++; }
        int st = p - a0;
        int l0 = lt*32, s0 = st*32;
        float (*Cs)[132] = (float(*)[132])SH;
        float (*Bs2)[132] = (float(*)[132])(SH + 16896);
        int ty = tid >> 4, tx = tid & 15;
        float acc[2][2];
        acc[0][0]=0.f; acc[0][1]=0.f; acc[1][0]=0.f; acc[1][1]=0.f;

        size_t rowC = ((size_t)(b*SEQ + c*CHUNK + l0))*256 + 128;
        size_t rowB = ((size_t)(b*SEQ + c*CHUNK + s0))*256;
        #pragma unroll
        for (int it=0; it<4; it++){
            int f = tid + it*256;
            int r = f >> 5, c4 = f & 31;
            *(float4*)&Cs[r][c4*4]  = *(const float4*)(xBC_BC + rowC + (size_t)r*256 + c4*4);
            *(float4*)&Bs2[r][c4*4] = *(const float4*)(xBC_BC + rowB + (size_t)r*256 + c4*4);
        }
        __syncthreads();
        #pragma unroll 8
        for (int k=0;k<128;k++){
            float a0v = Cs[ty*2][k],   a1v = Cs[ty*2+1][k];
            float b0v = Bs2[tx*2][k],  b1v = Bs2[tx*2+1][k];
            acc[0][0] += a0v*b0v; acc[0][1] += a0v*b1v;
            acc[1][0] += a1v*b0v; acc[1][1] += a1v*b1v;
        }
        size_t Gb = ((size_t)(b*NC + c)) << 16;
        #pragma unroll
        for (int i=0;i<2;i++){
            ushort2 g2;
            g2.x = f2bf(acc[i][0]); g2.y = f2bf(acc[i][1]);
            *(ushort2*)(G + Gb + (size_t)(l0 + ty*2 + i)*256 + s0 + tx*2) = g2;
        }
    }
}

// ---------------- inter-chunk recurrence (in place, bf16, 4-way split) --------------
__global__ __launch_bounds__(256) void recur_kernel(const float* __restrict__ A_cum,
                                                    us* __restrict__ states) {
    int h = blockIdx.x, b = blockIdx.y, z = blockIdx.z;
    int tid = threadIdx.x;
    float Srun[8];
    #pragma unroll
    for (int i=0;i<8;i++) Srun[i]=0.f;
    const float* acum = A_cum + ((size_t)b*NUM_HEADS + h)*SEQ;
    for (int c=0;c<NC;c++){
        float alast = acum[c*CHUNK + CHUNK-1];
        float dec = expf(alast);
        size_t base = ((size_t)((b*NC + c)*NUM_HEADS + h))*(HEAD_DIM*STATE);
        #pragma unroll
        for (int i=0;i<8;i++){
            size_t idx = base + (size_t)tid + (size_t)(z*8+i)*256;
            float raw = bf2f(states[idx]);
            states[idx] = f2bf(Srun[i]);
            Srun[i] = Srun[i]*dec + raw;
        }
    }
}

// ---------------- Y = e_l*(Cs @ St^T) + Gw @ Xs^T + D*X   (MFMA) --------------------
__global__ __launch_bounds__(256) void yscan_mfma(const us* __restrict__ G,
                                                  const us* __restrict__ Cb,
                                                  const us* __restrict__ XT,
                                                  const float* __restrict__ dtbuf,
                                                  const float* __restrict__ A_cum,
                                                  const us* __restrict__ statesT,
                                                  const float* __restrict__ Dvec,
                                                  us* __restrict__ projb) {
    int xb = blockIdx.x;
    int c = xb & 7, lt = xb >> 3;
    int h = blockIdx.y, b = blockIdx.z;
    int l0 = lt*64;
    __shared__ __align__(16) char pool[32768];
    us (*Cs)[128] = (us(*)[128])pool;
    us (*St)[128] = (us(*)[128])(pool + 16384);
    us (*Gw)[64]  = (us(*)[64])pool;
    us (*Xs)[64]  = (us(*)[64])(pool + 8192);
    float (*Ot)[68] = (float(*)[68])pool;
    __shared__ float ac[CHUNK], dts[CHUNK];
    int tid = threadIdx.x, lane = tid & 63, wid = tid >> 6;
    ac[tid]  = A_cum[((size_t)(b*NUM_HEADS + h))*SEQ + c*CHUNK + tid];
    dts[tid] = dtbuf[((size_t)(b*SEQ + c*CHUNK + tid))*NUM_HEADS + h];

    size_t stb = ((size_t)((b*NC + c)*NUM_HEADS + h))*(HEAD_DIM*STATE);
    #pragma unroll
    for (int q=0;q<4;q++){
        int brow = (wid*4+q)*4;
        int row  = brow + (lane>>4);
        int sl   = (lane&15) ^ (row & 7);
        gld16(Cb + ((size_t)(b*SEQ + c*CHUNK + l0 + row))*128 + sl*8, &Cs[brow][0]);
        gld16(statesT + stb + (size_t)row*128 + sl*8, &St[brow][0]);
    }
    __syncthreads();

    f32x4 acc1[4];
    #pragma unroll
    for (int j=0;j<4;j++) acc1[j] = (f32x4){0.f,0.f,0.f,0.f};
    #pragma unroll
    for (int kk=0; kk<128; kk+=32){
        int arow = wid*16 + (lane&15);
        int aslot = ((kk>>3)+(lane>>4)) ^ (arow&7);
        bf16x8 a = *(const bf16x8*)&Cs[arow][aslot*8];
        #pragma unroll
        for (int j=0;j<4;j++){
            int brow = j*16 + (lane&15);
            int bslot = ((kk>>3)+(lane>>4)) ^ (brow&7);
            bf16x8 bb = *(const bf16x8*)&St[brow][bslot*8];
            acc1[j] = MFMA16(a, bb, acc1[j]);
        }
    }
    float el[4];
    #pragma unroll
    for (int r=0;r<4;r++) el[r] = expf(ac[l0 + wid*16 + (lane>>4)*4 + r]);
    float master[4][4];
    #pragma unroll
    for (int j=0;j<4;j++)
        #pragma unroll
        for (int r=0;r<4;r++) master[j][r] = acc1[j][r]*el[r];
    __syncthreads();

    size_t Gb = ((size_t)(b*NC + c)) << 16;
    f32x4 acc2[4];
    #pragma unroll
    for (int j=0;j<4;j++) acc2[j] = (f32x4){0.f,0.f,0.f,0.f};
    for (int st=0; st<=lt; st++){
        int s0 = st*64;
        #pragma unroll
        for (int it=0; it<2; it++){
            int f = tid + it*256;
            int r = f >> 3, g = f & 7;
            uint4 v = *(const uint4*)(G + Gb + (size_t)(l0 + r)*256 + s0 + g*8);
            float e[8]; unpack8(v, e);
            float acl = ac[l0 + r];
            us o[8];
            #pragma unroll
            for (int u=0;u<8;u++){
                int s = s0 + g*8 + u;
                float w = (s <= l0 + r) ? expf(acl - ac[s])*dts[s] : 0.f;
                o[u] = f2bf(e[u]*w);
            }
            int slot = g ^ (r&7);
            *(ushort4*)&Gw[r][slot*8]   = *(ushort4*)&o[0];
            *(ushort4*)&Gw[r][slot*8+4] = *(ushort4*)&o[4];
        }
        #pragma unroll
        for (int q=0;q<2;q++){
            int brow = (wid*2+q)*8;
            int row  = brow + (lane>>3);
            int sl   = (lane&7) ^ (row&7);
            gld16(XT + ((size_t)(b*INTER + h*HEAD_DIM + row))*SEQ + c*CHUNK + s0 + sl*8,
                  &Xs[brow][0]);
        }
        __syncthreads();
        #pragma unroll
        for (int kk=0; kk<64; kk+=32){
            int arow = wid*16 + (lane&15);
            int aslot = ((kk>>3)+(lane>>4)) ^ (arow&7);
            bf16x8 a = *(const bf16x8*)&Gw[arow][aslot*8];
            #pragma unroll
            for (int j=0;j<4;j++){
                int brow = j*16 + (lane&15);
                int bslot = ((kk>>3)+(lane>>4)) ^ (brow&7);
                bf16x8 bb = *(const bf16x8*)&Xs[brow][bslot*8];
                acc2[j] = MFMA16(a, bb, acc2[j]);
            }
        }
        if (st < lt) __syncthreads();
    }

    float Dh = Dvec[h];
    #pragma unroll
    for (int j=0;j<4;j++){
        int p = j*16 + (lane&15);
        #pragma unroll
        for (int r=0;r<4;r++){
            int sl_ = wid*16 + (lane>>4)*4 + r;
            int slot = (sl_>>3) ^ (p&7);
            float xv = bf2f(Xs[p][slot*8 + (sl_&7)]);
            master[j][r] += acc2[j][r] + Dh*xv;
        }
    }
    __syncthreads();

    #pragma unroll
    for (int j=0;j<4;j++){
        int p = j*16 + (lane&15);
        #pragma unroll
        for (int r=0;r<4;r++)
            Ot[wid*16 + (lane>>4)*4 + r][p] = master[j][r];
    }
    __syncthreads();
    #pragma unroll
    for (int it=0; it<4; it++){
        int f = tid + it*256;
        int r = f >> 4, c4 = f & 15;
        ushort4 o;
        o.x = f2bf(Ot[r][c4*4+0]); o.y = f2bf(Ot[r][c4*4+1]);
        o.z = f2bf(Ot[r][c4*4+2]); o.w = f2bf(Ot[r][c4*4+3]);
        *(ushort4*)(projb + ((size_t)(b*SEQ + c*CHUNK + l0 + r))*PROJ_PAD + INTER + h*HEAD_DIM + c4*4) = o;
    }
}

// ---------------- gate * silu + RMSNorm -> packed bf16 y ----------------------------
__global__ __launch_bounds__(256) void gate_norm_kernel(const us* __restrict__ projb,
                                                        const float* __restrict__ normw,
                                                        us* __restrict__ yb) {
    int t = blockIdx.x;
    int tid = threadIdx.x;
    const us* row = projb + (size_t)t*PROJ_PAD;
    __shared__ float red[4];
    float vals[20];
    float ss = 0.f;
    #pragma unroll
    for (int i=0;i<5;i++){
        int j = (tid + i*256)*4;
        ushort4 g4 = *(const ushort4*)(row + j);
        ushort4 y4 = *(const ushort4*)(row + INTER + j);
        #pragma unroll
        for (int u=0;u<4;u++){
            float g = bf2f(((const us*)&g4)[u]);
            float y = bf2f(((const us*)&y4)[u]);
            float gv = g / (1.f + expf(-g));
            float v = y * gv;
            vals[i*4+u] = v;
            ss += v*v;
        }
    }
    #pragma unroll
    for (int off=32; off; off>>=1) ss += __shfl_xor(ss, off);
    if ((tid&63)==0) red[tid>>6] = ss;
    __syncthreads();
    float tot = red[0]+red[1]+red[2]+red[3];
    float inv = rsqrtf(tot/(float)INTER + EPS);
    #pragma unroll
    for (int i=0;i<5;i++){
        int j = (tid + i*256)*4;
        ushort4 o;
        o.x = f2bf(vals[i*4+0] * inv * normw[j+0]);
        o.y = f2bf(vals[i*4+1] * inv * normw[j+1]);
        o.z = f2bf(vals[i*4+2] * inv * normw[j+2]);
        o.w = f2bf(vals[i*4+3] * inv * normw[j+3]);
        *(ushort4*)(yb + (size_t)t*INTER + j) = o;
    }
}

// ------------------------------------------------------------------------------------
extern "C" void kernel_launch(void* const* d_in, const int* in_sizes, int n_in,
                              void* d_out, int out_size, void* d_ws, size_t ws_size,
                              hipStream_t stream) {
    const float* x        = (const float*)d_in[0];
    const float* in_w     = (const float*)d_in[1];
    const float* conv_w   = (const float*)d_in[2];
    const float* conv_b   = (const float*)d_in[3];
    const float* A_log    = (const float*)d_in[4];
    const float* Dvec     = (const float*)d_in[5];
    const float* dt_bias  = (const float*)d_in[6];
    const float* norm_w   = (const float*)d_in[7];
    const float* out_w    = (const float*)d_in[8];
    float* out = (float*)d_out;
    (void)ws_size; (void)n_in; (void)in_sizes; (void)out_size;

    const size_t PROJB   = (size_t)TOK*PROJ_PAD*2;
    const size_t PROJBCB = (size_t)TOK*NBC*4;
    const size_t XTB     = (size_t)TOK*INTER*2;
    const size_t XBCBCB  = (size_t)TOK*256*4;
    const size_t BTB     = (size_t)BATCH*128*SEQ*2;
    const size_t CBB     = (size_t)TOK*128*2;
    const size_t GBYTES  = (size_t)BATCH*NC*CHUNK*CHUNK*2;
    const size_t DTB     = (size_t)TOK*NUM_HEADS*4;
    const size_t ACUMB   = DTB;
    const size_t STB     = (size_t)BATCH*NC*NUM_HEADS*HEAD_DIM*STATE*2;
    const size_t XHB   = (size_t)TOK*HIDDEN*2;
    const size_t WBCB  = (size_t)NBCP*HIDDEN*2;
    const size_t YBB   = (size_t)TOK*INTER*2;

    char* base = (char*)d_ws;
    size_t off = 0;
    us* projb  = (us*)(base + off); off += PROJB;
    float* projBC = (float*)(base + off); off += PROJBCB;
    us* XTp    = (us*)(base + off); off += XTB;
    float* xBC_BC = (float*)(base + off); off += XBCBCB;
    us* BTp    = (us*)(base + off); off += BTB;
    us* Cbp    = (us*)(base + off); off += CBB;
    us* Gp     = (us*)(base + off); off += GBYTES;
    float* dtbuf = (float*)(base + off); off += DTB;
    float* A_cum = (float*)(base + off); off += ACUMB;
    us* statesT = (us*)(base + off); off += STB;
    char*  T   = base + off;
    us* xhi    = (us*)T;
    us* xlo    = (us*)(T + XHB);
    us* wbc_hi = (us*)(T + 2*XHB);
    us* wbc_lo = (us*)(T + 2*XHB + WBCB);
    us* w1b    = (us*)(T + 2*XHB + 2*WBCB);
    float* bcpart = (float*)w1b;
    us* yb     = (us*)T;
    us* w2b    = (us*)(T + YBB);

    // 1. fused prep
    {
        unsigned total_blocks = (unsigned)((N4A + N4B + N4C) / 256);
        prep_kernel<<<total_blocks, 256, 0, stream>>>(x, in_w, xhi, xlo, w1b, wbc_hi, wbc_lo);
    }
    // 2. proj(gate,X) = x @ w1^T  (256x256 8-phase deep pipeline)
    gemm1_8ph<<<dim3(PROJ_PAD/256, TOK/256), 512, 0, stream>>>(xhi, w1b, projb, PROJ_PAD);
    // 2b. B/C/dt via bf16 hi/lo split-K MFMA; partials alias w1b
    bc_splitk_mfma<<<dim3(NBCP/128, TOK/128, KSPL2), 256, 0, stream>>>(xhi, xlo, wbc_hi, wbc_lo, bcpart);
    // 3. reduce + conv_xt (merged)
    mega_red_convxt<<<RED_BLOCKS + CXT_BLOCKS, 256, 0, stream>>>(bcpart, dt_bias, projb,
                                                                 conv_w, conv_b,
                                                                 projBC, dtbuf, XTp);
    // 4. conv_bc + cumsum + w2 cvt (merged)
    mega_convbc_cum_w2<<<CBC_BLOCKS + CUM_BLOCKS + W2_BLOCKS, 256, 0, stream>>>(
        projBC, conv_w, conv_b, dtbuf, A_log, out_w, xBC_BC, BTp, Cbp, A_cum, w2b);
    // 5. states + g (merged)
    mega_states_g<<<ST_BLOCKS + GK_BLOCKS, 256, 0, stream>>>(XTp, BTp, dtbuf, A_cum, xBC_BC,
                                                             statesT, Gp);
    // 6. inter-chunk recurrence
    recur_kernel<<<dim3(NUM_HEADS, BATCH, 4), 256, 0, stream>>>(A_cum, statesT);
    // 7. Y (MFMA)
    yscan_mfma<<<dim3(NC*4, NUM_HEADS, BATCH), 256, 0, stream>>>(Gp, Cbp, XTp, dtbuf, A_cum,
                                                                 statesT, Dvec, projb);
    // 8. gate + RMSNorm
    gate_norm_kernel<<<TOK, 256, 0, stream>>>(projb, norm_w, yb);
    // 9. out = y @ out_w^T  (128x128, proven)
    gemm_bf16<false><<<dim3(HIDDEN/128, TOK/128), 256, 0, stream>>>(yb, INTER, w2b, INTER,
                                                                    out, HIDDEN, INTER);
}

// Round 16
// 704.411 us; speedup vs baseline: 1.0401x; 1.0401x over previous
//
#include <hip/hip_runtime.h>
#include <hip/hip_bf16.h>
#include <math.h>

#define HIDDEN   2560
#define NUM_HEADS 80
#define HEAD_DIM 64
#define STATE    128
#define CONV_K   4
#define CHUNK    256
#define INTER    (2*HIDDEN)                 // 5120
#define CONV_DIM (INTER + 2*STATE)          // 5376
#define PROJ     (INTER + CONV_DIM + NUM_HEADS) // 10576
#define PROJ_PAD 10240                      // gate + X only
#define NBC      336
#define NBCP     384
#define EPS      1e-5f

#define BATCH 2
#define SEQ   2048
#define TOK   (BATCH*SEQ)                   // 4096
#define NC    (SEQ/CHUNK)                   // 8
#define KSPL2 8
#define KCH2  (HIDDEN/KSPL2)                // 320

#define RED_BLOCKS 1536
#define CXT_BLOCKS 5120
#define CBC_BLOCKS 4096
#define CUM_BLOCKS 1280
#define W2_BLOCKS  12800
#define ST_BLOCKS  1280
#define GK_BLOCKS  576

typedef __attribute__((ext_vector_type(8))) short bf16x8;
typedef __attribute__((ext_vector_type(4))) float f32x4;
typedef unsigned short us;

#define MFMA16(a,b,c) __builtin_amdgcn_mfma_f32_16x16x32_bf16((a),(b),(c),0,0,0)

__device__ __forceinline__ us f2bf(float f){
    union{float f;unsigned u;}v; v.f=f;
    unsigned r = v.u + 0x7fffu + ((v.u>>16)&1u);
    return (us)(r>>16);
}
__device__ __forceinline__ float bf2f(us s){
    union{unsigned u;float f;}v; v.u = ((unsigned)s)<<16; return v.f;
}
__device__ __forceinline__ void unpack8(uint4 u, float* e){
    e[0]=bf2f((us)(u.x&0xffff)); e[1]=bf2f((us)(u.x>>16));
    e[2]=bf2f((us)(u.y&0xffff)); e[3]=bf2f((us)(u.y>>16));
    e[4]=bf2f((us)(u.z&0xffff)); e[5]=bf2f((us)(u.z>>16));
    e[6]=bf2f((us)(u.w&0xffff)); e[7]=bf2f((us)(u.w>>16));
}
__device__ __forceinline__ void gld16(const void* g, void* l){
    __builtin_amdgcn_global_load_lds((const __attribute__((address_space(1))) void*)g,
                                     (__attribute__((address_space(3))) void*)l, 16, 0, 0);
}

// =============== 128x128 bf16 MFMA GEMM (NT) — proven kernel ========================
template<bool BF16OUT>
__global__ __launch_bounds__(256) void gemm_bf16(const us* __restrict__ A, int lda,
                                                 const us* __restrict__ B, int ldb,
                                                 void* __restrict__ Cv, int ldc, int K) {
    __shared__ us As[128][64];
    __shared__ us Bs[128][64];
    int tid = threadIdx.x;
    int lane = tid & 63, wid = tid >> 6;
    int wr = wid >> 1, wc = wid & 1;

    int bm, bn;
    if ((gridDim.y & 7) == 0) {
        int bid   = blockIdx.y * gridDim.x + blockIdx.x;
        int xcd   = bid & 7;
        int local = bid >> 3;
        int mrows = gridDim.y >> 3;
        bm = (xcd * mrows + (local % mrows)) * 128;
        bn = (local / mrows) * 128;
    } else {
        bm = blockIdx.y * 128;
        bn = blockIdx.x * 128;
    }

    f32x4 acc[4][4];
    #pragma unroll
    for (int i=0;i<4;i++)
        #pragma unroll
        for (int j=0;j<4;j++) acc[i][j] = (f32x4){0.f,0.f,0.f,0.f};

    int srow_off = lane >> 3;
    int sslot    = lane & 7;

    for (int k0 = 0; k0 < K; k0 += 64) {
        #pragma unroll
        for (int q=0;q<4;q++){
            int brow = (wid*4+q)*8;
            int row  = brow + srow_off;
            int sl   = sslot ^ (row & 7);
            gld16(A + (size_t)(bm + row)*lda + k0 + sl*8, &As[brow][0]);
            gld16(B + (size_t)(bn + row)*ldb + k0 + sl*8, &Bs[brow][0]);
        }
        __syncthreads();
        #pragma unroll
        for (int kk=0; kk<64; kk+=32){
            bf16x8 a[4], b[4];
            #pragma unroll
            for (int i=0;i<4;i++){
                int row = wr*64 + i*16 + (lane&15);
                int slot = ((kk>>3) + (lane>>4)) ^ (row & 7);
                a[i] = *(const bf16x8*)&As[row][slot*8];
            }
            #pragma unroll
            for (int j=0;j<4;j++){
                int row = wc*64 + j*16 + (lane&15);
                int slot = ((kk>>3) + (lane>>4)) ^ (row & 7);
                b[j] = *(const bf16x8*)&Bs[row][slot*8];
            }
            #pragma unroll
            for (int i=0;i<4;i++)
                #pragma unroll
                for (int j=0;j<4;j++)
                    acc[i][j] = MFMA16(a[i], b[j], acc[i][j]);
        }
        __syncthreads();
    }
    #pragma unroll
    for (int i=0;i<4;i++){
        int row0 = bm + wr*64 + i*16 + (lane>>4)*4;
        #pragma unroll
        for (int j=0;j<4;j++){
            int col = bn + wc*64 + j*16 + (lane&15);
            #pragma unroll
            for (int r=0;r<4;r++){
                if (BF16OUT)
                    ((us*)Cv)[(size_t)(row0+r)*ldc + col] = f2bf(acc[i][j][r]);
                else
                    ((float*)Cv)[(size_t)(row0+r)*ldc + col] = acc[i][j][r];
            }
        }
    }
}

// =============== bf16 hi/lo split-K MFMA for B/C/dt (fp32-quality) ====================
__global__ __launch_bounds__(256) void bc_splitk_mfma(const us* __restrict__ xhi,
                                                      const us* __restrict__ xlo,
                                                      const us* __restrict__ whi,
                                                      const us* __restrict__ wlo,
                                                      float* __restrict__ Cpart) {
    __shared__ us As[128][64];
    __shared__ us Bs[128][64];
    int tid = threadIdx.x;
    int lane = tid & 63, wid = tid >> 6;
    int wr = wid >> 1, wc = wid & 1;
    int bn = blockIdx.x * 128, bm = blockIdx.y * 128, z = blockIdx.z;

    f32x4 acc[4][4];
    #pragma unroll
    for (int i=0;i<4;i++)
        #pragma unroll
        for (int j=0;j<4;j++) acc[i][j] = (f32x4){0.f,0.f,0.f,0.f};

    int srow_off = lane >> 3;
    int sslot    = lane & 7;

    for (int term = 0; term < 3; ++term){
        const us* A = (term==2) ? xlo : xhi;
        const us* B = (term==0) ? wlo : whi;
        for (int k0 = z*KCH2; k0 < z*KCH2 + KCH2; k0 += 64) {
            #pragma unroll
            for (int q=0;q<4;q++){
                int brow = (wid*4+q)*8;
                int row  = brow + srow_off;
                int sl   = sslot ^ (row & 7);
                gld16(A + (size_t)(bm + row)*HIDDEN + k0 + sl*8, &As[brow][0]);
                gld16(B + (size_t)(bn + row)*HIDDEN + k0 + sl*8, &Bs[brow][0]);
            }
            __syncthreads();
            #pragma unroll
            for (int kk=0; kk<64; kk+=32){
                bf16x8 a[4], b[4];
                #pragma unroll
                for (int i=0;i<4;i++){
                    int row = wr*64 + i*16 + (lane&15);
                    int slot = ((kk>>3) + (lane>>4)) ^ (row & 7);
                    a[i] = *(const bf16x8*)&As[row][slot*8];
                }
                #pragma unroll
                for (int j=0;j<4;j++){
                    int row = wc*64 + j*16 + (lane&15);
                    int slot = ((kk>>3) + (lane>>4)) ^ (row & 7);
                    b[j] = *(const bf16x8*)&Bs[row][slot*8];
                }
                #pragma unroll
                for (int i=0;i<4;i++)
                    #pragma unroll
                    for (int j=0;j<4;j++)
                        acc[i][j] = MFMA16(a[i], b[j], acc[i][j]);
            }
            __syncthreads();
        }
    }
    float* Cz = Cpart + (size_t)z*TOK*NBCP;
    #pragma unroll
    for (int i=0;i<4;i++){
        int row0 = bm + wr*64 + i*16 + (lane>>4)*4;
        #pragma unroll
        for (int j=0;j<4;j++){
            int col = bn + wc*64 + j*16 + (lane&15);
            #pragma unroll
            for (int r=0;r<4;r++)
                Cz[(size_t)(row0+r)*NBCP + col] = acc[i][j][r];
        }
    }
}

// ---------------- fused prep: x->(xhi,xlo), w1->bf16, wbc->(hi,lo) ------------------
#define N4A ((size_t)TOK*HIDDEN/4)
#define N4B ((size_t)PROJ_PAD*HIDDEN/4)
#define N4C ((size_t)NBCP*HIDDEN/4)
__global__ __launch_bounds__(256) void prep_kernel(const float* __restrict__ x,
                                                   const float* __restrict__ in_w,
                                                   us* __restrict__ xhi,
                                                   us* __restrict__ xlo,
                                                   us* __restrict__ w1b,
                                                   us* __restrict__ wbc_hi,
                                                   us* __restrict__ wbc_lo) {
    size_t gid = (size_t)blockIdx.x*256 + threadIdx.x;
    if (gid < N4A) {
        size_t i = gid*4;
        float4 v = *(const float4*)(x + i);
        float e[4] = {v.x, v.y, v.z, v.w};
        ushort4 h, l;
        us* hp = (us*)&h;
        us* lp = (us*)&l;
        #pragma unroll
        for (int u=0;u<4;u++){
            us hv = f2bf(e[u]);
            hp[u] = hv;
            lp[u] = f2bf(e[u] - bf2f(hv));
        }
        *(ushort4*)(xhi + i) = h;
        *(ushort4*)(xlo + i) = l;
    } else if (gid < N4A + N4B) {
        size_t i = (gid - N4A)*4;
        float4 v = *(const float4*)(in_w + i);
        ushort4 o;
        o.x=f2bf(v.x); o.y=f2bf(v.y); o.z=f2bf(v.z); o.w=f2bf(v.w);
        *(ushort4*)(w1b + i) = o;
    } else {
        size_t j = gid - N4A - N4B;
        size_t i = j*4;
        int row = (int)(i / HIDDEN);
        int kk  = (int)(i % HIDDEN);
        ushort4 h, l;
        h.x=h.y=h.z=h.w=0; l.x=l.y=l.z=l.w=0;
        if (row < NBC){
            float4 v = *(const float4*)(in_w + (size_t)(2*INTER + row)*HIDDEN + kk);
            float e[4] = {v.x, v.y, v.z, v.w};
            us* hp = (us*)&h;
            us* lp = (us*)&l;
            #pragma unroll
            for (int u=0;u<4;u++){
                us hv = f2bf(e[u]);
                hp[u] = hv;
                lp[u] = f2bf(e[u] - bf2f(hv));
            }
        }
        *(ushort4*)(wbc_hi + i) = h;
        *(ushort4*)(wbc_lo + i) = l;
    }
}

// =============== MERGED: reduce_bc2 + conv_xt =======================================
__global__ __launch_bounds__(256) void mega_red_convxt(const float* __restrict__ part,
                                                       const float* __restrict__ dt_bias,
                                                       const us* __restrict__ projb,
                                                       const float* __restrict__ cw,
                                                       const float* __restrict__ cb,
                                                       float* __restrict__ outBC,
                                                       float* __restrict__ dtbuf,
                                                       us* __restrict__ XT) {
    __shared__ us raw[68][66];
    int bid = blockIdx.x;
    int tid = threadIdx.x;
    if (bid < RED_BLOCKS) {
        size_t i4 = (size_t)bid*256 + tid;
        size_t i = i4*4;
        float4 s = *(const float4*)(part + i);
        #pragma unroll
        for (int z=1; z<KSPL2; z++){
            float4 v = *(const float4*)(part + (size_t)z*TOK*NBCP + i);
            s.x += v.x; s.y += v.y; s.z += v.z; s.w += v.w;
        }
        int col = (int)(i % NBCP);
        int t   = (int)(i / NBCP);
        if (col < 256) {
            *(float4*)(outBC + (size_t)t*NBC + col) = s;
        } else if (col < NBC) {
            int h = col - 256;
            float e[4] = {s.x, s.y, s.z, s.w};
            #pragma unroll
            for (int u=0;u<4;u++){
                float xv = e[u] + dt_bias[h+u];
                float sp = (xv > 20.f) ? xv : log1pf(expf(xv));
                e[u] = fminf(fmaxf(sp, 0.f), 100.f);
            }
            float4 o; o.x=e[0]; o.y=e[1]; o.z=e[2]; o.w=e[3];
            *(float4*)(dtbuf + (size_t)t*NUM_HEADS + h) = o;
        }
    } else {
        int b3 = bid - RED_BLOCKS;
        int bx = b3 & 63, by = b3 >> 6;
        int t0 = bx * 64, d0 = by * 64;
        int b  = t0 / SEQ;
        int s0 = t0 % SEQ;
        for (int f = tid; f < 67*8; f += 256){
            int r = f >> 3, g = f & 7;
            int sp = s0 - 3 + r;
            uint4 v;
            if (sp >= 0) v = *(const uint4*)(projb + ((size_t)(b*SEQ+sp))*PROJ_PAD + INTER + d0 + g*8);
            else { v.x=0u; v.y=0u; v.z=0u; v.w=0u; }
            unsigned int* dst = (unsigned int*)&raw[r][g*8];
            dst[0]=v.x; dst[1]=v.y; dst[2]=v.z; dst[3]=v.w;
        }
        __syncthreads();
        int t = tid & 63, dg = tid >> 6;
        #pragma unroll
        for (int dd = 0; dd < 16; dd++){
            int d = dg*16 + dd;
            float acc = cb[d0+d];
            #pragma unroll
            for (int j=0;j<CONV_K;j++)
                acc += cw[(d0+d)*CONV_K+j] * bf2f(raw[t+j][d]);
            float val = acc/(1.f+expf(-acc));
            XT[((size_t)(b*INTER + d0 + d))*SEQ + s0 + t] = f2bf(val);
        }
    }
}

// =============== MERGED: conv_bc + cumsum + w2 cvt ==================================
__global__ __launch_bounds__(256) void mega_convbc_cum_w2(const float* __restrict__ projBC,
                                                          const float* __restrict__ cw,
                                                          const float* __restrict__ cb,
                                                          const float* __restrict__ dtbuf,
                                                          const float* __restrict__ A_log,
                                                          const float* __restrict__ out_w,
                                                          float* __restrict__ xBC_BC,
                                                          us* __restrict__ BT,
                                                          us* __restrict__ Cb,
                                                          float* __restrict__ A_cum,
                                                          us* __restrict__ w2b) {
    __shared__ float buf[CHUNK];
    int bid = blockIdx.x;
    int tid = threadIdx.x;
    if (bid < CBC_BLOCKS) {
        int idx = bid*256 + tid;
        int d = idx & 255;
        int t = idx >> 8;
        int b = t / SEQ, sl = t % SEQ;
        int dc = INTER + d;
        float acc = cb[dc];
        #pragma unroll
        for (int j=0;j<CONV_K;j++){
            int sp = sl - (CONV_K-1) + j;
            if (sp >= 0)
                acc += cw[dc*CONV_K+j] * projBC[((size_t)(b*SEQ+sp))*NBC + d];
        }
        float val = acc / (1.f + expf(-acc));
        xBC_BC[(size_t)t*256 + d] = val;
        if (d < 128)
            BT[((size_t)(b*128 + d))*SEQ + sl] = f2bf(val);
        else
            Cb[(size_t)t*128 + (d-128)] = f2bf(val);
    } else if (bid < CBC_BLOCKS + CUM_BLOCKS) {
        int b4 = bid - CBC_BLOCKS;
        int c = b4 & 7, h = (b4 >> 3) % 80, b = b4 / 640;
        int l = tid;
        float A = -expf(A_log[h]);
        float v = A * dtbuf[(size_t)(b*SEQ + c*CHUNK + l)*NUM_HEADS + h];
        buf[l] = v;
        __syncthreads();
        for (int off=1; off<CHUNK; off<<=1){
            float t2 = (l>=off) ? buf[l-off] : 0.f;
            __syncthreads();
            buf[l] += t2;
            __syncthreads();
        }
        A_cum[((size_t)b*NUM_HEADS + h)*SEQ + c*CHUNK + l] = buf[l];
    } else {
        size_t i4 = (size_t)(bid - CBC_BLOCKS - CUM_BLOCKS)*256 + tid;
        size_t i = i4*4;
        float4 v = *(const float4*)(out_w + i);
        ushort4 o; o.x=f2bf(v.x); o.y=f2bf(v.y); o.z=f2bf(v.z); o.w=f2bf(v.w);
        *(ushort4*)(w2b + i) = o;
    }
}

// =============== MERGED: states_mfma + g_kernel =====================================
__global__ __launch_bounds__(256) void mega_states_g(const us* __restrict__ XT,
                                                     const us* __restrict__ BT,
                                                     const float* __restrict__ dtbuf,
                                                     const float* __restrict__ A_cum,
                                                     const float* __restrict__ xBC_BC,
                                                     us* __restrict__ statesT,
                                                     us* __restrict__ G) {
    __shared__ __align__(16) char SH[33792];
    int bid = blockIdx.x;
    int tid = threadIdx.x;
    if (bid < ST_BLOCKS) {
        int c = bid & 7, h = (bid >> 3) % 80, b = bid / 640;
        us (*Asx)[64] = (us(*)[64])SH;
        us (*Bs)[64]  = (us(*)[64])(SH + 8192);
        float* wl     = (float*)(SH + 24576);
        int lane = tid & 63, wid = tid >> 6;
        {
            const float* ac = A_cum + ((size_t)(b*NUM_HEADS+h))*SEQ + c*CHUNK;
            float Alast = ac[CHUNK-1];
            wl[tid] = expf(Alast - ac[tid]) * dtbuf[((size_t)(b*SEQ + c*CHUNK + tid))*NUM_HEADS + h];
        }
        __syncthreads();
        f32x4 acc[4][2];
        #pragma unroll
        for (int i=0;i<4;i++)
            #pragma unroll
            for (int j=0;j<2;j++) acc[i][j] = (f32x4){0.f,0.f,0.f,0.f};

        for (int kc = 0; kc < 4; kc++){
            int lbase = kc*64;
            #pragma unroll
            for (int q=0;q<4;q++){
                int brow = (wid*4+q)*8;
                int row  = brow + (lane>>3);
                int sl   = (lane&7) ^ (row & 7);
                gld16(BT + ((size_t)(b*128 + row))*SEQ + c*CHUNK + lbase + sl*8, &Bs[brow][0]);
            }
            #pragma unroll
            for (int it=0; it<2; it++){
                int f = tid + it*256;
                int r = f >> 3, g = f & 7;
                uint4 v = *(const uint4*)(XT + ((size_t)(b*INTER + h*HEAD_DIM + r))*SEQ + c*CHUNK + lbase + g*8);
                float e[8]; unpack8(v, e);
                us o[8];
                #pragma unroll
                for (int u=0;u<8;u++) o[u] = f2bf(e[u] * wl[lbase + g*8 + u]);
                int slot = g ^ (r & 7);
                *(ushort4*)&Asx[r][slot*8]   = *(ushort4*)&o[0];
                *(ushort4*)&Asx[r][slot*8+4] = *(ushort4*)&o[4];
            }
            __syncthreads();
            #pragma unroll
            for (int kk=0; kk<64; kk+=32){
                bf16x8 a[4], bb[2];
                #pragma unroll
                for (int i=0;i<4;i++){
                    int row = i*16 + (lane&15);
                    int slot = ((kk>>3)+(lane>>4)) ^ (row&7);
                    a[i] = *(const bf16x8*)&Asx[row][slot*8];
                }
                #pragma unroll
                for (int j=0;j<2;j++){
                    int row = wid*32 + j*16 + (lane&15);
                    int slot = ((kk>>3)+(lane>>4)) ^ (row&7);
                    bb[j] = *(const bf16x8*)&Bs[row][slot*8];
                }
                #pragma unroll
                for (int i=0;i<4;i++)
                    #pragma unroll
                    for (int j=0;j<2;j++)
                        acc[i][j] = MFMA16(a[i], bb[j], acc[i][j]);
            }
            __syncthreads();
        }
        size_t sb = ((size_t)((b*NC + c)*NUM_HEADS + h))*(HEAD_DIM*STATE);
        #pragma unroll
        for (int i=0;i<4;i++){
            #pragma unroll
            for (int j=0;j<2;j++){
                int n = wid*32 + j*16 + (lane&15);
                int p0 = i*16 + (lane>>4)*4;
                #pragma unroll
                for (int r=0;r<4;r++)
                    statesT[sb + (size_t)(p0+r)*128 + n] = f2bf(acc[i][j][r]);
            }
        }
    } else {
        int b5 = bid - ST_BLOCKS;
        int c = b5 & 7, p = (b5 >> 3) % 36, b = b5 / 288;
        int lt = 0, a0 = 0;
        while (a0 + lt + 1 <= p) { a0 += lt + 1; lt++; }
        int st = p - a0;
        int l0 = lt*32, s0 = st*32;
        float (*Cs)[132] = (float(*)[132])SH;
        float (*Bs2)[132] = (float(*)[132])(SH + 16896);
        int ty = tid >> 4, tx = tid & 15;
        float acc[2][2];
        acc[0][0]=0.f; acc[0][1]=0.f; acc[1][0]=0.f; acc[1][1]=0.f;

        size_t rowC = ((size_t)(b*SEQ + c*CHUNK + l0))*256 + 128;
        size_t rowB = ((size_t)(b*SEQ + c*CHUNK + s0))*256;
        #pragma unroll
        for (int it=0; it<4; it++){
            int f = tid + it*256;
            int r = f >> 5, c4 = f & 31;
            *(float4*)&Cs[r][c4*4]  = *(const float4*)(xBC_BC + rowC + (size_t)r*256 + c4*4);
            *(float4*)&Bs2[r][c4*4] = *(const float4*)(xBC_BC + rowB + (size_t)r*256 + c4*4);
        }
        __syncthreads();
        #pragma unroll 8
        for (int k=0;k<128;k++){
            float a0v = Cs[ty*2][k],   a1v = Cs[ty*2+1][k];
            float b0v = Bs2[tx*2][k],  b1v = Bs2[tx*2+1][k];
            acc[0][0] += a0v*b0v; acc[0][1] += a0v*b1v;
            acc[1][0] += a1v*b0v; acc[1][1] += a1v*b1v;
        }
        size_t Gb = ((size_t)(b*NC + c)) << 16;
        #pragma unroll
        for (int i=0;i<2;i++){
            ushort2 g2;
            g2.x = f2bf(acc[i][0]); g2.y = f2bf(acc[i][1]);
            *(ushort2*)(G + Gb + (size_t)(l0 + ty*2 + i)*256 + s0 + tx*2) = g2;
        }
    }
}

// ---------------- inter-chunk recurrence (in place, bf16, 4-way split) --------------
__global__ __launch_bounds__(256) void recur_kernel(const float* __restrict__ A_cum,
                                                    us* __restrict__ states) {
    int h = blockIdx.x, b = blockIdx.y, z = blockIdx.z;
    int tid = threadIdx.x;
    float Srun[8];
    #pragma unroll
    for (int i=0;i<8;i++) Srun[i]=0.f;
    const float* acum = A_cum + ((size_t)b*NUM_HEADS + h)*SEQ;
    for (int c=0;c<NC;c++){
        float alast = acum[c*CHUNK + CHUNK-1];
        float dec = expf(alast);
        size_t base = ((size_t)((b*NC + c)*NUM_HEADS + h))*(HEAD_DIM*STATE);
        #pragma unroll
        for (int i=0;i<8;i++){
            size_t idx = base + (size_t)tid + (size_t)(z*8+i)*256;
            float raw = bf2f(states[idx]);
            states[idx] = f2bf(Srun[i]);
            Srun[i] = Srun[i]*dec + raw;
        }
    }
}

// ---------------- Y = e_l*(Cs @ St^T) + Gw @ Xs^T + D*X   (MFMA) --------------------
__global__ __launch_bounds__(256) void yscan_mfma(const us* __restrict__ G,
                                                  const us* __restrict__ Cb,
                                                  const us* __restrict__ XT,
                                                  const float* __restrict__ dtbuf,
                                                  const float* __restrict__ A_cum,
                                                  const us* __restrict__ statesT,
                                                  const float* __restrict__ Dvec,
                                                  us* __restrict__ projb) {
    int xb = blockIdx.x;
    int c = xb & 7, lt = xb >> 3;
    int h = blockIdx.y, b = blockIdx.z;
    int l0 = lt*64;
    __shared__ __align__(16) char pool[32768];
    us (*Cs)[128] = (us(*)[128])pool;
    us (*St)[128] = (us(*)[128])(pool + 16384);
    us (*Gw)[64]  = (us(*)[64])pool;
    us (*Xs)[64]  = (us(*)[64])(pool + 8192);
    float (*Ot)[68] = (float(*)[68])pool;
    __shared__ float ac[CHUNK], dts[CHUNK];
    int tid = threadIdx.x, lane = tid & 63, wid = tid >> 6;
    ac[tid]  = A_cum[((size_t)(b*NUM_HEADS + h))*SEQ + c*CHUNK + tid];
    dts[tid] = dtbuf[((size_t)(b*SEQ + c*CHUNK + tid))*NUM_HEADS + h];

    size_t stb = ((size_t)((b*NC + c)*NUM_HEADS + h))*(HEAD_DIM*STATE);
    #pragma unroll
    for (int q=0;q<4;q++){
        int brow = (wid*4+q)*4;
        int row  = brow + (lane>>4);
        int sl   = (lane&15) ^ (row & 7);
        gld16(Cb + ((size_t)(b*SEQ + c*CHUNK + l0 + row))*128 + sl*8, &Cs[brow][0]);
        gld16(statesT + stb + (size_t)row*128 + sl*8, &St[brow][0]);
    }
    __syncthreads();

    f32x4 acc1[4];
    #pragma unroll
    for (int j=0;j<4;j++) acc1[j] = (f32x4){0.f,0.f,0.f,0.f};
    #pragma unroll
    for (int kk=0; kk<128; kk+=32){
        int arow = wid*16 + (lane&15);
        int aslot = ((kk>>3)+(lane>>4)) ^ (arow&7);
        bf16x8 a = *(const bf16x8*)&Cs[arow][aslot*8];
        #pragma unroll
        for (int j=0;j<4;j++){
            int brow = j*16 + (lane&15);
            int bslot = ((kk>>3)+(lane>>4)) ^ (brow&7);
            bf16x8 bb = *(const bf16x8*)&St[brow][bslot*8];
            acc1[j] = MFMA16(a, bb, acc1[j]);
        }
    }
    float el[4];
    #pragma unroll
    for (int r=0;r<4;r++) el[r] = expf(ac[l0 + wid*16 + (lane>>4)*4 + r]);
    float master[4][4];
    #pragma unroll
    for (int j=0;j<4;j++)
        #pragma unroll
        for (int r=0;r<4;r++) master[j][r] = acc1[j][r]*el[r];
    __syncthreads();

    size_t Gb = ((size_t)(b*NC + c)) << 16;
    f32x4 acc2[4];
    #pragma unroll
    for (int j=0;j<4;j++) acc2[j] = (f32x4){0.f,0.f,0.f,0.f};
    for (int st=0; st<=lt; st++){
        int s0 = st*64;
        #pragma unroll
        for (int it=0; it<2; it++){
            int f = tid + it*256;
            int r = f >> 3, g = f & 7;
            uint4 v = *(const uint4*)(G + Gb + (size_t)(l0 + r)*256 + s0 + g*8);
            float e[8]; unpack8(v, e);
            float acl = ac[l0 + r];
            us o[8];
            #pragma unroll
            for (int u=0;u<8;u++){
                int s = s0 + g*8 + u;
                float w = (s <= l0 + r) ? expf(acl - ac[s])*dts[s] : 0.f;
                o[u] = f2bf(e[u]*w);
            }
            int slot = g ^ (r&7);
            *(ushort4*)&Gw[r][slot*8]   = *(ushort4*)&o[0];
            *(ushort4*)&Gw[r][slot*8+4] = *(ushort4*)&o[4];
        }
        #pragma unroll
        for (int q=0;q<2;q++){
            int brow = (wid*2+q)*8;
            int row  = brow + (lane>>3);
            int sl   = (lane&7) ^ (row&7);
            gld16(XT + ((size_t)(b*INTER + h*HEAD_DIM + row))*SEQ + c*CHUNK + s0 + sl*8,
                  &Xs[brow][0]);
        }
        __syncthreads();
        #pragma unroll
        for (int kk=0; kk<64; kk+=32){
            int arow = wid*16 + (lane&15);
            int aslot = ((kk>>3)+(lane>>4)) ^ (arow&7);
            bf16x8 a = *(const bf16x8*)&Gw[arow][aslot*8];
            #pragma unroll
            for (int j=0;j<4;j++){
                int brow = j*16 + (lane&15);
                int bslot = ((kk>>3)+(lane>>4)) ^ (brow&7);
                bf16x8 bb = *(const bf16x8*)&Xs[brow][bslot*8];
                acc2[j] = MFMA16(a, bb, acc2[j]);
            }
        }
        if (st < lt) __syncthreads();
    }

    float Dh = Dvec[h];
    #pragma unroll
    for (int j=0;j<4;j++){
        int p = j*16 + (lane&15);
        #pragma unroll
        for (int r=0;r<4;r++){
            int sl_ = wid*16 + (lane>>4)*4 + r;
            int slot = (sl_>>3) ^ (p&7);
            float xv = bf2f(Xs[p][slot*8 + (sl_&7)]);
            master[j][r] += acc2[j][r] + Dh*xv;
        }
    }
    __syncthreads();

    #pragma unroll
    for (int j=0;j<4;j++){
        int p = j*16 + (lane&15);
        #pragma unroll
        for (int r=0;r<4;r++)
            Ot[wid*16 + (lane>>4)*4 + r][p] = master[j][r];
    }
    __syncthreads();
    #pragma unroll
    for (int it=0; it<4; it++){
        int f = tid + it*256;
        int r = f >> 4, c4 = f & 15;
        ushort4 o;
        o.x = f2bf(Ot[r][c4*4+0]); o.y = f2bf(Ot[r][c4*4+1]);
        o.z = f2bf(Ot[r][c4*4+2]); o.w = f2bf(Ot[r][c4*4+3]);
        *(ushort4*)(projb + ((size_t)(b*SEQ + c*CHUNK + l0 + r))*PROJ_PAD + INTER + h*HEAD_DIM + c4*4) = o;
    }
}

// ---------------- gate * silu + RMSNorm -> packed bf16 y ----------------------------
__global__ __launch_bounds__(256) void gate_norm_kernel(const us* __restrict__ projb,
                                                        const float* __restrict__ normw,
                                                        us* __restrict__ yb) {
    int t = blockIdx.x;
    int tid = threadIdx.x;
    const us* row = projb + (size_t)t*PROJ_PAD;
    __shared__ float red[4];
    float vals[20];
    float ss = 0.f;
    #pragma unroll
    for (int i=0;i<5;i++){
        int j = (tid + i*256)*4;
        ushort4 g4 = *(const ushort4*)(row + j);
        ushort4 y4 = *(const ushort4*)(row + INTER + j);
        #pragma unroll
        for (int u=0;u<4;u++){
            float g = bf2f(((const us*)&g4)[u]);
            float y = bf2f(((const us*)&y4)[u]);
            float gv = g / (1.f + expf(-g));
            float v = y * gv;
            vals[i*4+u] = v;
            ss += v*v;
        }
    }
    #pragma unroll
    for (int off=32; off; off>>=1) ss += __shfl_xor(ss, off);
    if ((tid&63)==0) red[tid>>6] = ss;
    __syncthreads();
    float tot = red[0]+red[1]+red[2]+red[3];
    float inv = rsqrtf(tot/(float)INTER + EPS);
    #pragma unroll
    for (int i=0;i<5;i++){
        int j = (tid + i*256)*4;
        ushort4 o;
        o.x = f2bf(vals[i*4+0] * inv * normw[j+0]);
        o.y = f2bf(vals[i*4+1] * inv * normw[j+1]);
        o.z = f2bf(vals[i*4+2] * inv * normw[j+2]);
        o.w = f2bf(vals[i*4+3] * inv * normw[j+3]);
        *(ushort4*)(yb + (size_t)t*INTER + j) = o;
    }
}

// ------------------------------------------------------------------------------------
extern "C" void kernel_launch(void* const* d_in, const int* in_sizes, int n_in,
                              void* d_out, int out_size, void* d_ws, size_t ws_size,
                              hipStream_t stream) {
    const float* x        = (const float*)d_in[0];
    const float* in_w     = (const float*)d_in[1];
    const float* conv_w   = (const float*)d_in[2];
    const float* conv_b   = (const float*)d_in[3];
    const float* A_log    = (const float*)d_in[4];
    const float* Dvec     = (const float*)d_in[5];
    const float* dt_bias  = (const float*)d_in[6];
    const float* norm_w   = (const float*)d_in[7];
    const float* out_w    = (const float*)d_in[8];
    float* out = (float*)d_out;
    (void)ws_size; (void)n_in; (void)in_sizes; (void)out_size;

    const size_t PROJB   = (size_t)TOK*PROJ_PAD*2;
    const size_t PROJBCB = (size_t)TOK*NBC*4;
    const size_t XTB     = (size_t)TOK*INTER*2;
    const size_t XBCBCB  = (size_t)TOK*256*4;
    const size_t BTB     = (size_t)BATCH*128*SEQ*2;
    const size_t CBB     = (size_t)TOK*128*2;
    const size_t GBYTES  = (size_t)BATCH*NC*CHUNK*CHUNK*2;
    const size_t DTB     = (size_t)TOK*NUM_HEADS*4;
    const size_t ACUMB   = DTB;
    const size_t STB     = (size_t)BATCH*NC*NUM_HEADS*HEAD_DIM*STATE*2;
    const size_t XHB   = (size_t)TOK*HIDDEN*2;
    const size_t WBCB  = (size_t)NBCP*HIDDEN*2;
    const size_t YBB   = (size_t)TOK*INTER*2;

    char* base = (char*)d_ws;
    size_t off = 0;
    us* projb  = (us*)(base + off); off += PROJB;
    float* projBC = (float*)(base + off); off += PROJBCB;
    us* XTp    = (us*)(base + off); off += XTB;
    float* xBC_BC = (float*)(base + off); off += XBCBCB;
    us* BTp    = (us*)(base + off); off += BTB;
    us* Cbp    = (us*)(base + off); off += CBB;
    us* Gp     = (us*)(base + off); off += GBYTES;
    float* dtbuf = (float*)(base + off); off += DTB;
    float* A_cum = (float*)(base + off); off += ACUMB;
    us* statesT = (us*)(base + off); off += STB;
    char*  T   = base + off;
    us* xhi    = (us*)T;
    us* xlo    = (us*)(T + XHB);
    us* wbc_hi = (us*)(T + 2*XHB);
    us* wbc_lo = (us*)(T + 2*XHB + WBCB);
    us* w1b    = (us*)(T + 2*XHB + 2*WBCB);
    float* bcpart = (float*)w1b;
    us* yb     = (us*)T;
    us* w2b    = (us*)(T + YBB);

    // 1. fused prep
    {
        unsigned total_blocks = (unsigned)((N4A + N4B + N4C) / 256);
        prep_kernel<<<total_blocks, 256, 0, stream>>>(x, in_w, xhi, xlo, w1b, wbc_hi, wbc_lo);
    }
    // 2. proj(gate,X) = x @ w1^T  (proven 128x128 kernel)
    gemm_bf16<true><<<dim3(PROJ_PAD/128, TOK/128), 256, 0, stream>>>(xhi, HIDDEN, w1b, HIDDEN,
                                                                     projb, PROJ_PAD, HIDDEN);
    // 2b. B/C/dt via bf16 hi/lo split-K MFMA; partials alias w1b
    bc_splitk_mfma<<<dim3(NBCP/128, TOK/128, KSPL2), 256, 0, stream>>>(xhi, xlo, wbc_hi, wbc_lo, bcpart);
    // 3. reduce + conv_xt (merged)
    mega_red_convxt<<<RED_BLOCKS + CXT_BLOCKS, 256, 0, stream>>>(bcpart, dt_bias, projb,
                                                                 conv_w, conv_b,
                                                                 projBC, dtbuf, XTp);
    // 4. conv_bc + cumsum + w2 cvt (merged)
    mega_convbc_cum_w2<<<CBC_BLOCKS + CUM_BLOCKS + W2_BLOCKS, 256, 0, stream>>>(
        projBC, conv_w, conv_b, dtbuf, A_log, out_w, xBC_BC, BTp, Cbp, A_cum, w2b);
    // 5. states + g (merged)
    mega_states_g<<<ST_BLOCKS + GK_BLOCKS, 256, 0, stream>>>(XTp, BTp, dtbuf, A_cum, xBC_BC,
                                                             statesT, Gp);
    // 6. inter-chunk recurrence
    recur_kernel<<<dim3(NUM_HEADS, BATCH, 4), 256, 0, stream>>>(A_cum, statesT);
    // 7. Y (MFMA)
    yscan_mfma<<<dim3(NC*4, NUM_HEADS, BATCH), 256, 0, stream>>>(Gp, Cbp, XTp, dtbuf, A_cum,
                                                                 statesT, Dvec, projb);
    // 8. gate + RMSNorm
    gate_norm_kernel<<<TOK, 256, 0, stream>>>(projb, norm_w, yb);
    // 9. out = y @ out_w^T
    gemm_bf16<false><<<dim3(HIDDEN/128, TOK/128), 256, 0, stream>>>(yb, INTER, w2b, INTER,
                                                                    out, HIDDEN, INTER);
}